// Round 18
// baseline (472.163 us; speedup 1.0000x reference)
//
#include <hip/hip_runtime.h>
#include <hip/hip_cooperative_groups.h>
#include <math.h>

namespace cg = cooperative_groups;

constexpr int kB = 4, kN = 2048, kC = 128, kH = 4, kHD = 32;
// kScale * log2(e): scores land directly in log2 domain (folded into Wq)
constexpr float kScaleLog2e = 0.17677669529663687f * 1.4426950408889634f;
constexpr int NP = 4, TILES = 8;  // split-K x4, 8 K-tiles of 64 (compile-time)

typedef __attribute__((ext_vector_type(8))) short bf16x8;
typedef __attribute__((ext_vector_type(4))) float f32x4;

__device__ __forceinline__ float exp2fast(float v) { return __builtin_amdgcn_exp2f(v); }
__device__ __forceinline__ unsigned int cvtpk(float lo, float hi) {
  unsigned int r;
  asm("v_cvt_pk_bf16_f32 %0, %1, %2" : "=v"(r) : "v"(lo), "v"(hi));
  return r;
}
__device__ __forceinline__ float bflo(unsigned int u) {
  union { unsigned int u; float f; } v; v.u = u << 16; return v.f;
}
__device__ __forceinline__ float bfhi(unsigned int u) {
  union { unsigned int u; float f; } v; v.u = u & 0xFFFF0000u; return v.f;
}

// 32 KB shared, unioned across phases
union SMem {
  struct {
    unsigned short Ksf[2][2][4][64][8];      // [buf][sub][kc][lane][8]   16 KB
    unsigned short Vtf[2][2][2][2][64][8];   // [buf][sub][dh][ct][lane][8] 16 KB
  } a;
  unsigned short xs[16][136];                // qkv x-tile
};

// ---------------- body: weights->bf16 (unit 0..63) ----------------
__device__ __forceinline__ void wconv_body(
    int unit, const float* __restrict__ Wq, const float* __restrict__ Wkv,
    const float* __restrict__ Wp, unsigned short* __restrict__ Wallb,
    unsigned short* __restrict__ Wpb) {
  const int i4 = (unit * 256 + threadIdx.x) * 4;  // 0..65532
  float4 v;
  unsigned short* dst;
  if (i4 < 16384) {
    v = *(const float4*)&Wq[i4];
    v.x *= kScaleLog2e; v.y *= kScaleLog2e; v.z *= kScaleLog2e; v.w *= kScaleLog2e;
    dst = Wallb + i4;
  } else if (i4 < 49152) {
    v = *(const float4*)&Wkv[i4 - 16384];
    dst = Wallb + i4;
  } else {
    v = *(const float4*)&Wp[i4 - 49152];
    dst = Wpb + (i4 - 49152);
  }
  *(uint2*)dst = make_uint2(cvtpk(v.x, v.y), cvtpk(v.z, v.w));
}

// ---------------- body: adjacency->bitmask (unit 0..511) ----------------
__device__ __forceinline__ void abit_body(
    int unit, const int* __restrict__ A, unsigned long long* __restrict__ Abits) {
  const int lane = threadIdx.x & 63;
  const int w0 = unit * 4 + (threadIdx.x >> 6);
  #pragma unroll 4
  for (int k = 0; k < 32; ++k) {
    const int idx = w0 + k * 2048;
    const int row = idx >> 5, c0 = (idx & 31) * 64;
    unsigned long long msk = __ballot(A[(size_t)row * kN + c0 + lane] > 0);
    if (lane == 0) Abits[idx] = msk;
  }
}

// ---------------- body: QKV projection (unit 0..511) ----------------
__device__ __forceinline__ void qkv_body(
    SMem& sm, int unit, const float* __restrict__ x,
    const unsigned short* __restrict__ Wallb, unsigned short* __restrict__ qws,
    unsigned short* __restrict__ kws, unsigned short* __restrict__ vtws) {
  const int t = threadIdx.x;
  const int row0 = unit * 16;
  const int b = row0 >> 11;
  {
    const int r = t >> 4, c = (t & 15) * 8;
    const float* src = x + (size_t)(row0 + r) * kC + c;
    float4 a = *(const float4*)src;
    float4 bb = *(const float4*)(src + 4);
    *(uint4*)&sm.xs[r][c] = make_uint4(cvtpk(a.x, a.y), cvtpk(a.z, a.w),
                                       cvtpk(bb.x, bb.y), cvtpk(bb.z, bb.w));
  }
  __syncthreads();
  const int w = t >> 6, l = t & 63, lr = l & 15, g = l >> 4;
  bf16x8 xf[4];
  #pragma unroll
  for (int s = 0; s < 4; ++s) xf[s] = *(const bf16x8*)&sm.xs[lr][s * 32 + g * 8];
  #pragma unroll
  for (int ci = 0; ci < 6; ++ci) {
    const int c0 = (w * 6 + ci) * 16;
    const unsigned short* wr = Wallb + (size_t)(c0 + lr) * kC + g * 8;
    f32x4 acc = {0.f, 0.f, 0.f, 0.f};
    if (c0 < 256) {  // q or k: D[m=col][n=xrow]
      #pragma unroll
      for (int s = 0; s < 4; ++s) {
        bf16x8 wf = *(const bf16x8*)(wr + s * 32);
        acc = __builtin_amdgcn_mfma_f32_16x16x32_bf16(wf, xf[s], acc, 0, 0, 0);
      }
      const int col0 = c0 + g * 4;
      const int h = (col0 & 127) >> 5, hd0 = col0 & 31;
      unsigned short* dst = (col0 < 128) ? qws : kws;
      uint2 pk = make_uint2(cvtpk(acc[0], acc[1]), cvtpk(acc[2], acc[3]));
      *(uint2*)&dst[((size_t)(b * kH + h) * kN + row0 + lr) * kHD + hd0] = pk;
    } else {         // v transposed: D[m=xrow][n=col]
      #pragma unroll
      for (int s = 0; s < 4; ++s) {
        bf16x8 wf = *(const bf16x8*)(wr + s * 32);
        acc = __builtin_amdgcn_mfma_f32_16x16x32_bf16(xf[s], wf, acc, 0, 0, 0);
      }
      const int d = (c0 - 256) + lr;
      uint2 pk = make_uint2(cvtpk(acc[0], acc[1]), cvtpk(acc[2], acc[3]));
      *(uint2*)&vtws[((size_t)(b * kH + (d >> 5)) * kHD + (d & 31)) * kN + row0 + g * 4] = pk;
    }
  }
}

// ---------------- body: MFMA flash attention (r16 verbatim, parameterized) ----------
__device__ __forceinline__ void attn_body(
    SMem& sm, int bh, int qblk, int z, const unsigned short* __restrict__ qws,
    const unsigned short* __restrict__ kws, const unsigned short* __restrict__ vtws,
    const unsigned long long* __restrict__ Abits,
    unsigned short* __restrict__ Opart, float* __restrict__ lws) {
  const int t = threadIdx.x, w = t >> 6, l = t & 63, lr = l & 15, g = l >> 4;
  const int q0 = qblk * 128;
  const int qa = q0 + w * 32 + lr, qb = qa + 16;
  const int kt0 = z * TILES;
  const unsigned short* kbase = kws + (size_t)bh * kN * kHD;
  const unsigned short* vbase = vtws + (size_t)bh * kHD * kN;
  bf16x8 qf0 = *(const bf16x8*)&qws[((size_t)bh * kN + qa) * kHD + g * 8];
  bf16x8 qf1 = *(const bf16x8*)&qws[((size_t)bh * kN + qb) * kHD + g * 8];
  const unsigned long long* arow0 = Abits + (size_t)qa * (kN / 64) + kt0;
  const unsigned long long* arow1 = Abits + (size_t)qb * (kN / 64) + kt0;

  // K staging with permuted row map sigma; LDS dest linear-in-lane.
  const int skc = t >> 6, sl = t & 63;
  const int srow = sl & 15;
  const int scol = (skc >> 1) * 32 + (srow >> 2) * 8 + (skc & 1) * 4 + (srow & 3);
  const unsigned short* kfp = kbase + (size_t)kt0 * 64 * kHD +
                              (size_t)scol * kHD + (sl >> 4) * 8;
  const int sdh = t >> 7, sct = (t >> 6) & 1;
  const unsigned short* vfp = vbase + ((size_t)(sdh * 16 + (sl & 15))) * kN +
                              kt0 * 64 + sct * 32 + (sl >> 4) * 8;

  bf16x8 kr0 = *(const bf16x8*)kfp;
  bf16x8 kr1 = *(const bf16x8*)(kfp + (size_t)64 * kHD);
  bf16x8 vr0 = *(const bf16x8*)vfp;
  bf16x8 vr1 = *(const bf16x8*)(vfp + 64);
  *(bf16x8*)&sm.a.Ksf[0][0][skc][sl][0] = kr0;
  *(bf16x8*)&sm.a.Ksf[0][1][skc][sl][0] = kr1;
  *(bf16x8*)&sm.a.Vtf[0][0][sdh][sct][sl][0] = vr0;
  *(bf16x8*)&sm.a.Vtf[0][1][sdh][sct][sl][0] = vr1;
  unsigned long long mw0s[2] = {arow0[0], arow0[1]};
  unsigned long long mw1s[2] = {arow1[0], arow1[1]};
  unsigned long long mw0n[2], mw1n[2];

  f32x4 o0a = {0.f, 0.f, 0.f, 0.f}, o1a = o0a, o2a = o0a;
  f32x4 o0b = o0a, o1b = o0a, o2b = o0a;
  bf16x8 ones;
  #pragma unroll
  for (int i = 0; i < 8; ++i) ones[i] = (short)0x3F80;  // 1.0 bf16
  const int gsh = g * 8;  // lane's 8-col group within each 32-col half

  #pragma unroll
  for (int pr = 0; pr < TILES / 2; ++pr) {
    const int c = pr & 1;
    // prefetch next pair BEFORE the barrier (registers only, no LDS hazard)
    if (pr + 1 < TILES / 2) {
      kr0 = *(const bf16x8*)(kfp + (size_t)(2 * pr + 2) * 64 * kHD);
      kr1 = *(const bf16x8*)(kfp + (size_t)(2 * pr + 3) * 64 * kHD);
      vr0 = *(const bf16x8*)(vfp + (2 * pr + 2) * 64);
      vr1 = *(const bf16x8*)(vfp + (2 * pr + 3) * 64);
      mw0n[0] = arow0[2 * pr + 2]; mw0n[1] = arow0[2 * pr + 3];
      mw1n[0] = arow1[2 * pr + 2]; mw1n[1] = arow1[2 * pr + 3];
    }
    __syncthreads();  // buf c (written end of prev pair) visible; buf c^1 free
    #pragma unroll
    for (int s = 0; s < 2; ++s) {
      const unsigned int wlo0 = ((unsigned int)mw0s[s]) >> gsh;
      const unsigned int whi0 = ((unsigned int)(mw0s[s] >> 32)) >> gsh;
      const unsigned int wlo1 = ((unsigned int)mw1s[s]) >> gsh;
      const unsigned int whi1 = ((unsigned int)(mw1s[s] >> 32)) >> gsh;

      // QK^T + softmax + in-register pack into PV B-frags.
      // Output (kc,i) of lane (g,lr) = tile-col (kc>>1)*32 + g*8 + (kc&1)*4 + i.
      unsigned int pk0[2][4], pk1[2][4];  // [ct][p] - all indices compile-time
      #pragma unroll
      for (int kc = 0; kc < 4; ++kc) {
        bf16x8 kf = *(const bf16x8*)&sm.a.Ksf[c][s][kc][l][0];
        f32x4 z4 = {0.f, 0.f, 0.f, 0.f};
        f32x4 acc0 = __builtin_amdgcn_mfma_f32_16x16x32_bf16(kf, qf0, z4, 0, 0, 0);
        f32x4 acc1 = __builtin_amdgcn_mfma_f32_16x16x32_bf16(kf, qf1, z4, 0, 0, 0);
        const unsigned int word0 = (kc < 2) ? wlo0 : whi0;  // ct = kc>>1
        const unsigned int word1 = (kc < 2) ? wlo1 : whi1;
        float p0[4], p1[4];
        #pragma unroll
        for (int i = 0; i < 4; ++i) {
          float e0 = exp2fast(acc0[i]);
          float e1 = exp2fast(acc1[i]);
          int m0, m1;  // bit (kc&1)*4+i of word -> 0 or -1
          asm("v_bfe_i32 %0, %1, %2, 1" : "=v"(m0) : "v"(word0), "n"((kc & 1) * 4 + i));
          asm("v_bfe_i32 %0, %1, %2, 1" : "=v"(m1) : "v"(word1), "n"((kc & 1) * 4 + i));
          union { float f; int u; } u0, u1;
          u0.f = e0; u0.u &= m0; p0[i] = u0.f;
          u1.f = e1; u1.u &= m1; p1[i] = u1.f;
        }
        pk0[kc >> 1][(kc & 1) * 2]     = cvtpk(p0[0], p0[1]);
        pk0[kc >> 1][(kc & 1) * 2 + 1] = cvtpk(p0[2], p0[3]);
        pk1[kc >> 1][(kc & 1) * 2]     = cvtpk(p1[0], p1[1]);
        pk1[kc >> 1][(kc & 1) * 2 + 1] = cvtpk(p1[2], p1[3]);
      }
      #pragma unroll
      for (int ct = 0; ct < 2; ++ct) {
        union { uint4 u; bf16x8 v; } pb0, pb1;
        pb0.u = make_uint4(pk0[ct][0], pk0[ct][1], pk0[ct][2], pk0[ct][3]);
        pb1.u = make_uint4(pk1[ct][0], pk1[ct][1], pk1[ct][2], pk1[ct][3]);
        bf16x8 va = *(const bf16x8*)&sm.a.Vtf[c][s][0][ct][l][0];
        bf16x8 vb = *(const bf16x8*)&sm.a.Vtf[c][s][1][ct][l][0];
        o0a = __builtin_amdgcn_mfma_f32_16x16x32_bf16(va, pb0.v, o0a, 0, 0, 0);
        o1a = __builtin_amdgcn_mfma_f32_16x16x32_bf16(vb, pb0.v, o1a, 0, 0, 0);
        o2a = __builtin_amdgcn_mfma_f32_16x16x32_bf16(ones, pb0.v, o2a, 0, 0, 0);
        o0b = __builtin_amdgcn_mfma_f32_16x16x32_bf16(va, pb1.v, o0b, 0, 0, 0);
        o1b = __builtin_amdgcn_mfma_f32_16x16x32_bf16(vb, pb1.v, o1b, 0, 0, 0);
        o2b = __builtin_amdgcn_mfma_f32_16x16x32_bf16(ones, pb1.v, o2b, 0, 0, 0);
      }
    }
    if (pr + 1 < TILES / 2) {
      *(bf16x8*)&sm.a.Ksf[c ^ 1][0][skc][sl][0] = kr0;
      *(bf16x8*)&sm.a.Ksf[c ^ 1][1][skc][sl][0] = kr1;
      *(bf16x8*)&sm.a.Vtf[c ^ 1][0][sdh][sct][sl][0] = vr0;
      *(bf16x8*)&sm.a.Vtf[c ^ 1][1][sdh][sct][sl][0] = vr1;
      mw0s[0] = mw0n[0]; mw0s[1] = mw0n[1];
      mw1s[0] = mw1n[0]; mw1s[1] = mw1n[1];
    }
  }

  unsigned short* orow0 = Opart + ((size_t)(z * 16 + bh) * kN + qa) * kHD;
  unsigned short* orow1 = Opart + ((size_t)(z * 16 + bh) * kN + qb) * kHD;
  *(uint2*)&orow0[g * 4]      = make_uint2(cvtpk(o0a[0], o0a[1]), cvtpk(o0a[2], o0a[3]));
  *(uint2*)&orow0[16 + g * 4] = make_uint2(cvtpk(o1a[0], o1a[1]), cvtpk(o1a[2], o1a[3]));
  *(uint2*)&orow1[g * 4]      = make_uint2(cvtpk(o0b[0], o0b[1]), cvtpk(o0b[2], o0b[3]));
  *(uint2*)&orow1[16 + g * 4] = make_uint2(cvtpk(o1b[0], o1b[1]), cvtpk(o1b[2], o1b[3]));
  if (g == 0) {
    lws[(size_t)(z * 16 + bh) * kN + qa] = o2a[0];
    lws[(size_t)(z * 16 + bh) * kN + qb] = o2b[0];
  }
}

// ---------------- body: combine partials + out-proj + bias + residual ----------
__device__ __forceinline__ void proj_body(
    int unit, const unsigned short* __restrict__ Opart, const float* __restrict__ lws,
    const unsigned short* __restrict__ Wpb, const float* __restrict__ bp,
    const float* __restrict__ x, float* __restrict__ out) {
  const int t = threadIdx.x, w = t >> 6, l = t & 63, lr = l & 15, g = l >> 4;
  const int row0 = unit * 16;
  const int b = row0 >> 11;
  bf16x8 af[4];
  #pragma unroll
  for (int s = 0; s < 4; ++s) {
    const int bh = b * kH + s;
    float a0 = 0.f, a1 = 0.f, a2 = 0.f, a3 = 0.f, a4 = 0.f, a5 = 0.f, a6 = 0.f, a7 = 0.f;
    float lacc = 0.f;
    #pragma unroll
    for (int p = 0; p < NP; ++p) {
      const size_t base = (size_t)(p * 16 + bh) * kN + row0 + lr;
      const uint4 u = *(const uint4*)&Opart[base * kHD + g * 8];
      lacc += lws[base];
      a0 += bflo(u.x); a1 += bfhi(u.x);
      a2 += bflo(u.y); a3 += bfhi(u.y);
      a4 += bflo(u.z); a5 += bfhi(u.z);
      a6 += bflo(u.w); a7 += bfhi(u.w);
    }
    const float inv = 1.f / fmaxf(lacc, 1e-30f);
    union { uint4 u; bf16x8 v; } cv;
    cv.u = make_uint4(cvtpk(a0 * inv, a1 * inv), cvtpk(a2 * inv, a3 * inv),
                      cvtpk(a4 * inv, a5 * inv), cvtpk(a6 * inv, a7 * inv));
    af[s] = cv.v;
  }
  #pragma unroll
  for (int ci = 0; ci < 2; ++ci) {
    const int c0 = (w * 2 + ci) * 16;
    const unsigned short* wr = Wpb + (size_t)(c0 + lr) * kC + g * 8;
    f32x4 acc = {0.f, 0.f, 0.f, 0.f};
    #pragma unroll
    for (int s = 0; s < 4; ++s) {
      bf16x8 wf = *(const bf16x8*)(wr + s * 32);
      acc = __builtin_amdgcn_mfma_f32_16x16x32_bf16(wf, af[s], acc, 0, 0, 0);
    }
    const int col0 = c0 + g * 4;
    const size_t off = (size_t)(row0 + lr) * kC + col0;
    const float4 xb = *(const float4*)&x[off];
    const float4 bb = *(const float4*)&bp[col0];
    float4 r;
    r.x = acc[0] + bb.x + xb.x;
    r.y = acc[1] + bb.y + xb.y;
    r.z = acc[2] + bb.z + xb.z;
    r.w = acc[3] + bb.w + xb.w;
    *(float4*)&out[off] = r;
  }
}

// ---------------- fused cooperative kernel: 512 blocks = 2/CU co-resident ---------
// Device-scope fences around each grid.sync(): per-XCD L2s are not coherent;
// __threadfence() (agent scope) writes back + invalidates so producer data is
// visible across XCDs (the missing piece in the round-9 attempt).
__global__ __launch_bounds__(256) void fused_kernel(
    const float* __restrict__ x, const int* __restrict__ A,
    const float* __restrict__ Wq, const float* __restrict__ Wkv,
    const float* __restrict__ Wp, const float* __restrict__ bp,
    unsigned short* __restrict__ qws, unsigned short* __restrict__ kws,
    unsigned short* __restrict__ vtws, unsigned long long* __restrict__ Abits,
    unsigned short* __restrict__ Wallb, unsigned short* __restrict__ Wpb,
    float* __restrict__ lws, unsigned short* __restrict__ Opart,
    float* __restrict__ out) {
  __shared__ SMem sm;
  cg::grid_group grid = cg::this_grid();
  const int b = blockIdx.x;
  // P0: adjacency bitmask (all 512) + weight conversion (blocks 0..63)
  abit_body(b, A, Abits);
  if (b < 64) wconv_body(b, Wq, Wkv, Wp, Wallb, Wpb);
  __threadfence(); grid.sync(); __threadfence();
  // P1: QKV projection
  qkv_body(sm, b, x, Wallb, qws, kws, vtws);
  __threadfence(); grid.sync(); __threadfence();
  // P2: attention, two jobs per block (j = b -> z in {0,1}; j = b+512 -> z+2)
  attn_body(sm, b & 15, (b >> 4) & 15, b >> 8, qws, kws, vtws, Abits, Opart, lws);
  __syncthreads();  // job1 LDS reads done before job2 overwrites
  attn_body(sm, b & 15, (b >> 4) & 15, (b >> 8) + 2, qws, kws, vtws, Abits, Opart, lws);
  __threadfence(); grid.sync(); __threadfence();
  // P3: out projection + bias + residual
  proj_body(b, Opart, lws, Wpb, bp, x, out);
}

// ---------------- fallback wrappers (proven r16 4-dispatch path) ----------------
__global__ __launch_bounds__(256) void p_prep(
    const int* A, const float* Wq, const float* Wkv, const float* Wp,
    unsigned long long* Abits, unsigned short* Wallb, unsigned short* Wpb) {
  if (blockIdx.x < 512) abit_body(blockIdx.x, A, Abits);
  else wconv_body(blockIdx.x - 512, Wq, Wkv, Wp, Wallb, Wpb);
}
__global__ __launch_bounds__(256) void p_qkv(
    const float* x, const unsigned short* Wallb, unsigned short* qws,
    unsigned short* kws, unsigned short* vtws) {
  __shared__ SMem sm;
  qkv_body(sm, blockIdx.x, x, Wallb, qws, kws, vtws);
}
__global__ __launch_bounds__(256) void p_attn(
    const unsigned short* qws, const unsigned short* kws, const unsigned short* vtws,
    const unsigned long long* Abits, unsigned short* Opart, float* lws) {
  __shared__ SMem sm;
  attn_body(sm, blockIdx.x, blockIdx.y, blockIdx.z, qws, kws, vtws, Abits, Opart, lws);
}
__global__ __launch_bounds__(256) void p_proj(
    const unsigned short* Opart, const float* lws, const unsigned short* Wpb,
    const float* bp, const float* x, float* out) {
  proj_body(blockIdx.x, Opart, lws, Wpb, bp, x, out);
}

extern "C" void kernel_launch(void* const* d_in, const int* in_sizes, int n_in,
                              void* d_out, int out_size, void* d_ws, size_t ws_size,
                              hipStream_t stream) {
  const float* x   = (const float*)d_in[0];
  const int*   A   = (const int*)d_in[1];
  const float* Wq  = (const float*)d_in[2];
  const float* Wkv = (const float*)d_in[3];
  const float* Wp  = (const float*)d_in[4];
  const float* bp  = (const float*)d_in[5];
  float* out = (float*)d_out;
  char* ws = (char*)d_ws;

  // layout: qws 0..2M | kws 2..4M | vtws 4..6M | Abits 6..6.5M |
  //         Wallb+Wpb 6.5..6.625M | lws 7..7.5M | Opart 8..16M (np=4, bf16)
  unsigned short* qws   = (unsigned short*)(ws);
  unsigned short* kws   = (unsigned short*)(ws + (2u << 20));
  unsigned short* vtws  = (unsigned short*)(ws + (4u << 20));
  unsigned long long* Abits = (unsigned long long*)(ws + (6u << 20));
  unsigned short* Wallb = (unsigned short*)(ws + (6u << 20) + (1u << 19));
  unsigned short* Wpb   = Wallb + 384 * 128;
  float*          lws   = (float*)(ws + (7u << 20));
  unsigned short* Opart = (unsigned short*)(ws + (8u << 20));

  void* args[] = {(void*)&x, (void*)&A, (void*)&Wq, (void*)&Wkv, (void*)&Wp,
                  (void*)&bp, (void*)&qws, (void*)&kws, (void*)&vtws,
                  (void*)&Abits, (void*)&Wallb, (void*)&Wpb, (void*)&lws,
                  (void*)&Opart, (void*)&out};
  hipError_t err = hipLaunchCooperativeKernel((const void*)fused_kernel, dim3(512),
                                              dim3(256), args, 0, stream);
  if (err != hipSuccess) {
    (void)hipGetLastError();  // clear; use the proven 4-dispatch path
    p_prep<<<dim3(576), dim3(256), 0, stream>>>(A, Wq, Wkv, Wp, Abits, Wallb, Wpb);
    p_qkv<<<dim3(512), dim3(256), 0, stream>>>(x, Wallb, qws, kws, vtws);
    p_attn<<<dim3(16, 16, NP), dim3(256), 0, stream>>>(
        qws, kws, vtws, Abits, Opart, lws);
    p_proj<<<dim3(512), dim3(256), 0, stream>>>(Opart, lws, Wpb, bp, x, out);
  }
}

// Round 19
// 54.380 us; speedup vs baseline: 8.6826x; 8.6826x over previous
//
#include <hip/hip_runtime.h>
#include <math.h>

constexpr int kB = 4, kN = 2048, kC = 128, kH = 4, kHD = 32;
// kScale * log2(e): scores land directly in log2 domain (folded into Wq)
constexpr float kScaleLog2e = 0.17677669529663687f * 1.4426950408889634f;
constexpr int NP = 4, TILES = 8;  // split-K x4, 8 K-tiles of 64 (compile-time)

typedef __attribute__((ext_vector_type(8))) short bf16x8;
typedef __attribute__((ext_vector_type(4))) float f32x4;

__device__ __forceinline__ float exp2fast(float v) { return __builtin_amdgcn_exp2f(v); }
__device__ __forceinline__ unsigned int cvtpk(float lo, float hi) {
  unsigned int r;
  asm("v_cvt_pk_bf16_f32 %0, %1, %2" : "=v"(r) : "v"(lo), "v"(hi));
  return r;
}
__device__ __forceinline__ float bflo(unsigned int u) {
  union { unsigned int u; float f; } v; v.u = u << 16; return v.f;
}
__device__ __forceinline__ float bfhi(unsigned int u) {
  union { unsigned int u; float f; } v; v.u = u & 0xFFFF0000u; return v.f;
}

// ---------------- Kernel 0: adjacency->bitmask (0..511) + weights->bf16 (512..575) --
// Wallb rows: 0..127 = Wq*kScaleLog2e, 128..255 = Wkv[K], 256..383 = Wkv[V]
__global__ __launch_bounds__(256) void prep_kernel(
    const int* __restrict__ A, const float* __restrict__ Wq,
    const float* __restrict__ Wkv, const float* __restrict__ Wp,
    unsigned long long* __restrict__ Abits, unsigned short* __restrict__ Wallb,
    unsigned short* __restrict__ Wpb) {
  const int bid = blockIdx.x;
  if (bid < 512) {
    const int lane = threadIdx.x & 63;
    const int w0 = bid * 4 + (threadIdx.x >> 6);
    #pragma unroll 4
    for (int k = 0; k < 32; ++k) {
      const int idx = w0 + k * 2048;
      const int row = idx >> 5, c0 = (idx & 31) * 64;
      unsigned long long msk = __ballot(A[(size_t)row * kN + c0 + lane] > 0);
      if (lane == 0) Abits[idx] = msk;
    }
  } else {
    const int i4 = ((bid - 512) * 256 + threadIdx.x) * 4;  // 0..65532
    float4 v;
    unsigned short* dst;
    if (i4 < 16384) {
      v = *(const float4*)&Wq[i4];
      v.x *= kScaleLog2e; v.y *= kScaleLog2e; v.z *= kScaleLog2e; v.w *= kScaleLog2e;
      dst = Wallb + i4;
    } else if (i4 < 49152) {
      v = *(const float4*)&Wkv[i4 - 16384];
      dst = Wallb + i4;
    } else {
      v = *(const float4*)&Wp[i4 - 49152];
      dst = Wpb + (i4 - 49152);
    }
    *(uint2*)dst = make_uint2(cvtpk(v.x, v.y), cvtpk(v.z, v.w));
  }
}

// ---------------- Kernel 1: QKV projection via MFMA, bf16 weights ----------------
__global__ __launch_bounds__(256) void qkv_kernel(
    const float* __restrict__ x, const unsigned short* __restrict__ Wallb,
    unsigned short* __restrict__ qws, unsigned short* __restrict__ kws,
    unsigned short* __restrict__ vtws) {
  __shared__ unsigned short xs[16][136];
  const int t = threadIdx.x;
  const int row0 = blockIdx.x * 16;
  const int b = row0 >> 11;
  {
    const int r = t >> 4, c = (t & 15) * 8;
    const float* src = x + (size_t)(row0 + r) * kC + c;
    float4 a = *(const float4*)src;
    float4 bb = *(const float4*)(src + 4);
    *(uint4*)&xs[r][c] = make_uint4(cvtpk(a.x, a.y), cvtpk(a.z, a.w),
                                    cvtpk(bb.x, bb.y), cvtpk(bb.z, bb.w));
  }
  __syncthreads();
  const int w = t >> 6, l = t & 63, lr = l & 15, g = l >> 4;
  bf16x8 xf[4];
  #pragma unroll
  for (int s = 0; s < 4; ++s) xf[s] = *(const bf16x8*)&xs[lr][s * 32 + g * 8];
  #pragma unroll
  for (int ci = 0; ci < 6; ++ci) {
    const int c0 = (w * 6 + ci) * 16;
    const unsigned short* wr = Wallb + (size_t)(c0 + lr) * kC + g * 8;
    f32x4 acc = {0.f, 0.f, 0.f, 0.f};
    if (c0 < 256) {  // q or k: D[m=col][n=xrow]
      #pragma unroll
      for (int s = 0; s < 4; ++s) {
        bf16x8 wf = *(const bf16x8*)(wr + s * 32);
        acc = __builtin_amdgcn_mfma_f32_16x16x32_bf16(wf, xf[s], acc, 0, 0, 0);
      }
      const int col0 = c0 + g * 4;           // 4 consecutive cols, same head
      const int h = (col0 & 127) >> 5, hd0 = col0 & 31;
      unsigned short* dst = (col0 < 128) ? qws : kws;
      uint2 pk = make_uint2(cvtpk(acc[0], acc[1]), cvtpk(acc[2], acc[3]));
      *(uint2*)&dst[((size_t)(b * kH + h) * kN + row0 + lr) * kHD + hd0] = pk;
    } else {         // v transposed: D[m=xrow][n=col]
      #pragma unroll
      for (int s = 0; s < 4; ++s) {
        bf16x8 wf = *(const bf16x8*)(wr + s * 32);
        acc = __builtin_amdgcn_mfma_f32_16x16x32_bf16(xf[s], wf, acc, 0, 0, 0);
      }
      const int d = (c0 - 256) + lr;          // Vt row
      uint2 pk = make_uint2(cvtpk(acc[0], acc[1]), cvtpk(acc[2], acc[3]));
      *(uint2*)&vtws[((size_t)(b * kH + (d >> 5)) * kHD + (d & 31)) * kN + row0 + g * 4] = pk;
    }
  }
}

// ---------------- Kernel 2: MFMA flash attention, paired-tile staging ----------------
// grid (16=bh, 16=qblk, 4=z) x 256. 4 waves x 32 q-rows. K staged with permuted
// row map sigma so QK^T outputs land on PV's B-fragment k-slots (P in-register).
// TWO K-tiles staged per rendezvous -> 4 barriers/block instead of 8; prefetch
// of the next pair issues BEFORE the barrier (2 tiles of compute to hide under).
__global__ __launch_bounds__(256) void attn_kernel(
    const unsigned short* __restrict__ qws, const unsigned short* __restrict__ kws,
    const unsigned short* __restrict__ vtws,
    const unsigned long long* __restrict__ Abits,
    unsigned short* __restrict__ Opart, float* __restrict__ lws) {
  __shared__ unsigned short Ksf[2][2][4][64][8];        // [buf][sub][kc][lane][8]
  __shared__ unsigned short Vtf[2][2][2][2][64][8];     // [buf][sub][dhalf][ct][lane][8]
  const int t = threadIdx.x, w = t >> 6, l = t & 63, lr = l & 15, g = l >> 4;
  const int bh = blockIdx.x, qblk = blockIdx.y, z = blockIdx.z;
  const int q0 = qblk * 128;
  const int qa = q0 + w * 32 + lr, qb = qa + 16;
  const int kt0 = z * TILES;
  const unsigned short* kbase = kws + (size_t)bh * kN * kHD;
  const unsigned short* vbase = vtws + (size_t)bh * kHD * kN;
  bf16x8 qf0 = *(const bf16x8*)&qws[((size_t)bh * kN + qa) * kHD + g * 8];
  bf16x8 qf1 = *(const bf16x8*)&qws[((size_t)bh * kN + qb) * kHD + g * 8];
  const unsigned long long* arow0 = Abits + (size_t)qa * (kN / 64) + kt0;
  const unsigned long long* arow1 = Abits + (size_t)qb * (kN / 64) + kt0;

  // K staging with permuted row map sigma; LDS dest linear-in-lane.
  const int skc = t >> 6, sl = t & 63;
  const int srow = sl & 15;
  const int scol = (skc >> 1) * 32 + (srow >> 2) * 8 + (skc & 1) * 4 + (srow & 3);
  const unsigned short* kfp = kbase + (size_t)kt0 * 64 * kHD +
                              (size_t)scol * kHD + (sl >> 4) * 8;
  const int sdh = t >> 7, sct = (t >> 6) & 1;
  const unsigned short* vfp = vbase + ((size_t)(sdh * 16 + (sl & 15))) * kN +
                              kt0 * 64 + sct * 32 + (sl >> 4) * 8;

  bf16x8 kr0 = *(const bf16x8*)kfp;
  bf16x8 kr1 = *(const bf16x8*)(kfp + (size_t)64 * kHD);
  bf16x8 vr0 = *(const bf16x8*)vfp;
  bf16x8 vr1 = *(const bf16x8*)(vfp + 64);
  *(bf16x8*)&Ksf[0][0][skc][sl][0] = kr0;
  *(bf16x8*)&Ksf[0][1][skc][sl][0] = kr1;
  *(bf16x8*)&Vtf[0][0][sdh][sct][sl][0] = vr0;
  *(bf16x8*)&Vtf[0][1][sdh][sct][sl][0] = vr1;
  unsigned long long mw0s[2] = {arow0[0], arow0[1]};
  unsigned long long mw1s[2] = {arow1[0], arow1[1]};
  unsigned long long mw0n[2], mw1n[2];

  f32x4 o0a = {0.f, 0.f, 0.f, 0.f}, o1a = o0a, o2a = o0a;
  f32x4 o0b = o0a, o1b = o0a, o2b = o0a;
  bf16x8 ones;
  #pragma unroll
  for (int i = 0; i < 8; ++i) ones[i] = (short)0x3F80;  // 1.0 bf16
  const int gsh = g * 8;  // lane's 8-col group within each 32-col half

  #pragma unroll
  for (int pr = 0; pr < TILES / 2; ++pr) {
    const int c = pr & 1;
    // prefetch next pair BEFORE the barrier (registers only, no LDS hazard)
    if (pr + 1 < TILES / 2) {
      kr0 = *(const bf16x8*)(kfp + (size_t)(2 * pr + 2) * 64 * kHD);
      kr1 = *(const bf16x8*)(kfp + (size_t)(2 * pr + 3) * 64 * kHD);
      vr0 = *(const bf16x8*)(vfp + (2 * pr + 2) * 64);
      vr1 = *(const bf16x8*)(vfp + (2 * pr + 3) * 64);
      mw0n[0] = arow0[2 * pr + 2]; mw0n[1] = arow0[2 * pr + 3];
      mw1n[0] = arow1[2 * pr + 2]; mw1n[1] = arow1[2 * pr + 3];
    }
    __syncthreads();  // buf c (written end of prev pair) visible; buf c^1 free
    #pragma unroll
    for (int s = 0; s < 2; ++s) {
      const unsigned int wlo0 = ((unsigned int)mw0s[s]) >> gsh;
      const unsigned int whi0 = ((unsigned int)(mw0s[s] >> 32)) >> gsh;
      const unsigned int wlo1 = ((unsigned int)mw1s[s]) >> gsh;
      const unsigned int whi1 = ((unsigned int)(mw1s[s] >> 32)) >> gsh;

      // QK^T + softmax + in-register pack into PV B-frags.
      // Output (kc,i) of lane (g,lr) = tile-col (kc>>1)*32 + g*8 + (kc&1)*4 + i.
      unsigned int pk0[2][4], pk1[2][4];  // [ct][p] - all indices compile-time
      #pragma unroll
      for (int kc = 0; kc < 4; ++kc) {
        bf16x8 kf = *(const bf16x8*)&Ksf[c][s][kc][l][0];
        f32x4 z4 = {0.f, 0.f, 0.f, 0.f};
        f32x4 acc0 = __builtin_amdgcn_mfma_f32_16x16x32_bf16(kf, qf0, z4, 0, 0, 0);
        f32x4 acc1 = __builtin_amdgcn_mfma_f32_16x16x32_bf16(kf, qf1, z4, 0, 0, 0);
        const unsigned int word0 = (kc < 2) ? wlo0 : whi0;  // ct = kc>>1
        const unsigned int word1 = (kc < 2) ? wlo1 : whi1;
        float p0[4], p1[4];
        #pragma unroll
        for (int i = 0; i < 4; ++i) {
          float e0 = exp2fast(acc0[i]);
          float e1 = exp2fast(acc1[i]);
          int m0, m1;  // bit (kc&1)*4+i of word -> 0 or -1
          asm("v_bfe_i32 %0, %1, %2, 1" : "=v"(m0) : "v"(word0), "n"((kc & 1) * 4 + i));
          asm("v_bfe_i32 %0, %1, %2, 1" : "=v"(m1) : "v"(word1), "n"((kc & 1) * 4 + i));
          union { float f; int u; } u0, u1;
          u0.f = e0; u0.u &= m0; p0[i] = u0.f;
          u1.f = e1; u1.u &= m1; p1[i] = u1.f;
        }
        pk0[kc >> 1][(kc & 1) * 2]     = cvtpk(p0[0], p0[1]);
        pk0[kc >> 1][(kc & 1) * 2 + 1] = cvtpk(p0[2], p0[3]);
        pk1[kc >> 1][(kc & 1) * 2]     = cvtpk(p1[0], p1[1]);
        pk1[kc >> 1][(kc & 1) * 2 + 1] = cvtpk(p1[2], p1[3]);
      }
      #pragma unroll
      for (int ct = 0; ct < 2; ++ct) {
        union { uint4 u; bf16x8 v; } pb0, pb1;
        pb0.u = make_uint4(pk0[ct][0], pk0[ct][1], pk0[ct][2], pk0[ct][3]);
        pb1.u = make_uint4(pk1[ct][0], pk1[ct][1], pk1[ct][2], pk1[ct][3]);
        bf16x8 va = *(const bf16x8*)&Vtf[c][s][0][ct][l][0];
        bf16x8 vb = *(const bf16x8*)&Vtf[c][s][1][ct][l][0];
        o0a = __builtin_amdgcn_mfma_f32_16x16x32_bf16(va, pb0.v, o0a, 0, 0, 0);
        o1a = __builtin_amdgcn_mfma_f32_16x16x32_bf16(vb, pb0.v, o1a, 0, 0, 0);
        o2a = __builtin_amdgcn_mfma_f32_16x16x32_bf16(ones, pb0.v, o2a, 0, 0, 0);
        o0b = __builtin_amdgcn_mfma_f32_16x16x32_bf16(va, pb1.v, o0b, 0, 0, 0);
        o1b = __builtin_amdgcn_mfma_f32_16x16x32_bf16(vb, pb1.v, o1b, 0, 0, 0);
        o2b = __builtin_amdgcn_mfma_f32_16x16x32_bf16(ones, pb1.v, o2b, 0, 0, 0);
      }
    }
    if (pr + 1 < TILES / 2) {
      *(bf16x8*)&Ksf[c ^ 1][0][skc][sl][0] = kr0;
      *(bf16x8*)&Ksf[c ^ 1][1][skc][sl][0] = kr1;
      *(bf16x8*)&Vtf[c ^ 1][0][sdh][sct][sl][0] = vr0;
      *(bf16x8*)&Vtf[c ^ 1][1][sdh][sct][sl][0] = vr1;
      mw0s[0] = mw0n[0]; mw0s[1] = mw0n[1];
      mw1s[0] = mw1n[0]; mw1s[1] = mw1n[1];
    }
  }

  unsigned short* orow0 = Opart + ((size_t)(z * 16 + bh) * kN + qa) * kHD;
  unsigned short* orow1 = Opart + ((size_t)(z * 16 + bh) * kN + qb) * kHD;
  *(uint2*)&orow0[g * 4]      = make_uint2(cvtpk(o0a[0], o0a[1]), cvtpk(o0a[2], o0a[3]));
  *(uint2*)&orow0[16 + g * 4] = make_uint2(cvtpk(o1a[0], o1a[1]), cvtpk(o1a[2], o1a[3]));
  *(uint2*)&orow1[g * 4]      = make_uint2(cvtpk(o0b[0], o0b[1]), cvtpk(o0b[2], o0b[3]));
  *(uint2*)&orow1[16 + g * 4] = make_uint2(cvtpk(o1b[0], o1b[1]), cvtpk(o1b[2], o1b[3]));
  if (g == 0) {
    lws[(size_t)(z * 16 + bh) * kN + qa] = o2a[0];
    lws[(size_t)(z * 16 + bh) * kN + qb] = o2b[0];
  }
}

// ---------------- Kernel 3: combine partials + out-proj MFMA + bias + residual ----
__global__ __launch_bounds__(256) void proj_kernel(
    const unsigned short* __restrict__ Opart, const float* __restrict__ lws,
    const unsigned short* __restrict__ Wpb, const float* __restrict__ bp,
    const float* __restrict__ x, float* __restrict__ out) {
  const int t = threadIdx.x, w = t >> 6, l = t & 63, lr = l & 15, g = l >> 4;
  const int row0 = blockIdx.x * 16;
  const int b = row0 >> 11;
  bf16x8 af[4];
  #pragma unroll
  for (int s = 0; s < 4; ++s) {
    const int bh = b * kH + s;
    float a0 = 0.f, a1 = 0.f, a2 = 0.f, a3 = 0.f, a4 = 0.f, a5 = 0.f, a6 = 0.f, a7 = 0.f;
    float lacc = 0.f;
    #pragma unroll
    for (int p = 0; p < NP; ++p) {
      const size_t base = (size_t)(p * 16 + bh) * kN + row0 + lr;
      const uint4 u = *(const uint4*)&Opart[base * kHD + g * 8];
      lacc += lws[base];
      a0 += bflo(u.x); a1 += bfhi(u.x);
      a2 += bflo(u.y); a3 += bfhi(u.y);
      a4 += bflo(u.z); a5 += bfhi(u.z);
      a6 += bflo(u.w); a7 += bfhi(u.w);
    }
    const float inv = 1.f / fmaxf(lacc, 1e-30f);
    union { uint4 u; bf16x8 v; } cv;
    cv.u = make_uint4(cvtpk(a0 * inv, a1 * inv), cvtpk(a2 * inv, a3 * inv),
                      cvtpk(a4 * inv, a5 * inv), cvtpk(a6 * inv, a7 * inv));
    af[s] = cv.v;
  }
  #pragma unroll
  for (int ci = 0; ci < 2; ++ci) {
    const int c0 = (w * 2 + ci) * 16;
    const unsigned short* wr = Wpb + (size_t)(c0 + lr) * kC + g * 8;
    f32x4 acc = {0.f, 0.f, 0.f, 0.f};
    #pragma unroll
    for (int s = 0; s < 4; ++s) {
      bf16x8 wf = *(const bf16x8*)(wr + s * 32);
      acc = __builtin_amdgcn_mfma_f32_16x16x32_bf16(wf, af[s], acc, 0, 0, 0);
    }
    const int col0 = c0 + g * 4;
    const size_t off = (size_t)(row0 + lr) * kC + col0;
    const float4 xb = *(const float4*)&x[off];
    const float4 bb = *(const float4*)&bp[col0];
    float4 r;
    r.x = acc[0] + bb.x + xb.x;
    r.y = acc[1] + bb.y + xb.y;
    r.z = acc[2] + bb.z + xb.z;
    r.w = acc[3] + bb.w + xb.w;
    *(float4*)&out[off] = r;
  }
}

extern "C" void kernel_launch(void* const* d_in, const int* in_sizes, int n_in,
                              void* d_out, int out_size, void* d_ws, size_t ws_size,
                              hipStream_t stream) {
  const float* x   = (const float*)d_in[0];
  const int*   A   = (const int*)d_in[1];
  const float* Wq  = (const float*)d_in[2];
  const float* Wkv = (const float*)d_in[3];
  const float* Wp  = (const float*)d_in[4];
  const float* bp  = (const float*)d_in[5];
  float* out = (float*)d_out;
  char* ws = (char*)d_ws;

  // layout: qws 0..2M | kws 2..4M | vtws 4..6M | Abits 6..6.5M |
  //         Wallb+Wpb 6.5..6.625M | lws 7..7.5M | Opart 8..16M (np=4, bf16)
  unsigned short* qws   = (unsigned short*)(ws);
  unsigned short* kws   = (unsigned short*)(ws + (2u << 20));
  unsigned short* vtws  = (unsigned short*)(ws + (4u << 20));
  unsigned long long* Abits = (unsigned long long*)(ws + (6u << 20));
  unsigned short* Wallb = (unsigned short*)(ws + (6u << 20) + (1u << 19));
  unsigned short* Wpb   = Wallb + 384 * 128;
  float*          lws   = (float*)(ws + (7u << 20));
  unsigned short* Opart = (unsigned short*)(ws + (8u << 20));

  prep_kernel<<<dim3(576), dim3(256), 0, stream>>>(A, Wq, Wkv, Wp, Abits, Wallb, Wpb);
  qkv_kernel<<<dim3(512), dim3(256), 0, stream>>>(x, Wallb, qws, kws, vtws);
  attn_kernel<<<dim3(16, 16, NP), dim3(256), 0, stream>>>(
      qws, kws, vtws, Abits, Opart, lws);
  proj_kernel<<<dim3(512), dim3(256), 0, stream>>>(Opart, lws, Wpb, bp, x, out);
}